// Round 3
// baseline (186.810 us; speedup 1.0000x reference)
//
#include <hip/hip_runtime.h>
#include <math.h>

// ManifoldAlignmentLoss: B=256, D=512, N=50000, A=8, K=5
// R7 = R6 structure (4 kernels -> 3), with hipMemsetAsync replaced by a
// zeroing kernel (suspected graph-capture tripwire: R6 run died in-harness
// with no counters).
//   - zero_kernel: zeroes per-b counters + out (pure kernel launch).
//   - match_kernel: packs target attrs from tattr itself, buckets matches
//     BY B: bucket[b][slot]=n via global atomic counters[b].
//   - dot_topk_kernel: block b normalizes z row b in registers, computes all
//     its pair dots (64 x 16-lane groups, 8 independent float4 loads/lane),
//     sims in LDS, wave-0 top-5 extraction, one atomicAdd to out.
// Rationale: R5 showed dot restructure moved nothing -> per-kernel compute is
// ~20-25us total; the rest of our ~52us (after ~123us harness poison fills)
// is launch serialization + intermediate global round-trips. Cut both.

constexpr int D = 512;
constexpr int A = 8;
constexpr int K_NEI = 5;
constexpr int SLOTS = 512;        // per-b bucket capacity (mean ~130)
constexpr int CSTRIDE = 16;       // counter padding: 64B per counter line

__device__ __forceinline__ unsigned pack_attrs(const int4 x, const int4 y) {
    return  ((unsigned)x.x & 0xFu)        | (((unsigned)x.y & 0xFu) << 4)
          | (((unsigned)x.z & 0xFu) << 8)  | (((unsigned)x.w & 0xFu) << 12)
          | (((unsigned)y.x & 0xFu) << 16) | (((unsigned)y.y & 0xFu) << 20)
          | (((unsigned)y.z & 0xFu) << 24) | (((unsigned)y.w & 0xFu) << 28);
}

// ---------------- zero: counters + out --------------------------------------
// grid = 16 blocks x 256 threads (covers B*CSTRIDE = 4096 ints)
__global__ __launch_bounds__(256) void zero_kernel(
    int* __restrict__ counters, float* __restrict__ out, int total)
{
    const int i = blockIdx.x * 256 + threadIdx.x;
    if (i < total) counters[i] = 0;
    if (i == 0) out[0] = 0.0f;
}

// ---------------- match: one thread per train row, bucket by b -------------
// grid = ceil(N/256) blocks x 256 threads
__global__ __launch_bounds__(256) void match_kernel(
    const int* __restrict__ trattr, const int* __restrict__ tattr,
    unsigned* __restrict__ bucket, int* __restrict__ counters, int N)
{
    __shared__ unsigned s_tp[256];

    const int tid = threadIdx.x;
    const int n = blockIdx.x * 256 + tid;

    // pack all 256 target patterns from tattr directly (8KB, L2-resident)
    {
        const int4* t4 = (const int4*)(tattr + (size_t)tid * A);
        s_tp[tid] = pack_attrs(t4[0], t4[1]);
    }
    __syncthreads();

    if (n < N) {
        const int4* a4 = (const int4*)(trattr + (size_t)n * A);
        const unsigned p = pack_attrs(a4[0], a4[1]);

        const uint4* tp4 = (const uint4*)s_tp;
        #pragma unroll 4
        for (int bq = 0; bq < 64; bq++) {
            const uint4 t = tp4[bq];
            #pragma unroll
            for (int j = 0; j < 4; j++) {
                const unsigned tv = (j == 0) ? t.x : (j == 1) ? t.y : (j == 2) ? t.z : t.w;
                const unsigned yv = p ^ tv;
                // hi bit of each nibble set iff nibble nonzero
                const unsigned nzhi = ((((yv & 0x77777777u) + 0x77777777u) | yv) & 0x88888888u);
                if (__popc(nzhi) <= 1) {   // >= A-1 matching attrs
                    const int b = bq * 4 + j;
                    const int idx = atomicAdd(&counters[b * CSTRIDE], 1);
                    if (idx < SLOTS) bucket[(size_t)b * SLOTS + idx] = (unsigned)n;
                }
            }
        }
    }
}

// ---------------- dot+topk: one block per b ---------------------------------
// grid = B blocks x 1024 threads (64 x 16-lane groups)
__global__ __launch_bounds__(1024) void dot_topk_kernel(
    const float* __restrict__ train, const float* __restrict__ z,
    const unsigned* __restrict__ bucket, const int* __restrict__ counters,
    float* __restrict__ out, int Bt)
{
    __shared__ float s_sims[SLOTS];

    const int b = blockIdx.x;
    const int tid = threadIdx.x;
    const int lane = tid & 15;           // lane within 16-lane group
    const int grp = tid >> 4;            // 0..63
    constexpr int NGRP = 64;

    // --- normalize z row b entirely in registers (each group holds full row)
    const float4* z4 = (const float4*)(z + (size_t)b * D);
    float4 zz[8];
    #pragma unroll
    for (int j = 0; j < 8; j++) zz[j] = z4[j * 16 + lane];
    float zs = 0.0f;
    #pragma unroll
    for (int j = 0; j < 8; j++)
        zs += zz[j].x*zz[j].x + zz[j].y*zz[j].y + zz[j].z*zz[j].z + zz[j].w*zz[j].w;
    #pragma unroll
    for (int m = 1; m < 16; m <<= 1) zs += __shfl_xor(zs, m, 64);
    const float zscale = 1.0f / fmaxf(sqrtf(zs), 1e-12f);
    #pragma unroll
    for (int j = 0; j < 8; j++) {
        zz[j].x *= zscale; zz[j].y *= zscale; zz[j].z *= zscale; zz[j].w *= zscale;
    }

    const int cnt = counters[b * CSTRIDE];
    const int m = min(cnt, SLOTS);

    for (int i = grp; i < m; i += NGRP) {
        const int n = (int)bucket[(size_t)b * SLOTS + i];
        const float4* __restrict__ row4 = (const float4*)(train + (size_t)n * D);
        float4 r[8];
        #pragma unroll
        for (int j = 0; j < 8; j++) r[j] = row4[j * 16 + lane];

        float ss = 0.0f, dd = 0.0f;
        #pragma unroll
        for (int j = 0; j < 8; j++) {
            ss += r[j].x*r[j].x  + r[j].y*r[j].y  + r[j].z*r[j].z  + r[j].w*r[j].w;
            dd += r[j].x*zz[j].x + r[j].y*zz[j].y + r[j].z*zz[j].z + r[j].w*zz[j].w;
        }
        #pragma unroll
        for (int mm = 1; mm < 16; mm <<= 1) {
            ss += __shfl_xor(ss, mm, 64);
            dd += __shfl_xor(dd, mm, 64);
        }
        if (lane == 0) s_sims[i] = dd / fmaxf(sqrtf(ss), 1e-12f);
    }
    __syncthreads();

    // --- top-5 extraction on wave 0 only
    if (tid < 64) {
        float v[8];
        #pragma unroll
        for (int k = 0; k < 8; k++) {
            const int i = tid + k * 64;
            v[k] = (i < m) ? s_sims[i] : -1e30f;
        }

        float s = 0.0f;
        #pragma unroll
        for (int r = 0; r < K_NEI; r++) {
            float best = v[0];
            #pragma unroll
            for (int k = 1; k < 8; k++) best = fmaxf(best, v[k]);
            float M = best;
            #pragma unroll
            for (int mm = 1; mm < 64; mm <<= 1) M = fmaxf(M, __shfl_xor(M, mm, 64));
            s += fmaxf(M, 0.0f);   // N-cnt exact zeros from unmatched entries dominate negatives
            const unsigned long long bal = __ballot(best == M);
            const int first = __ffsll(bal) - 1;
            if (tid == first) {
                if      (v[0] == M) v[0] = -1e30f;
                else if (v[1] == M) v[1] = -1e30f;
                else if (v[2] == M) v[2] = -1e30f;
                else if (v[3] == M) v[3] = -1e30f;
                else if (v[4] == M) v[4] = -1e30f;
                else if (v[5] == M) v[5] = -1e30f;
                else if (v[6] == M) v[6] = -1e30f;
                else                v[7] = -1e30f;
            }
        }

        if (tid == 0) {
            const float contrib = (cnt >= K_NEI) ? (1.0f - s * (1.0f / K_NEI)) : 0.0f;
            atomicAdd(out, contrib / (float)Bt);
        }
    }
}

extern "C" void kernel_launch(void* const* d_in, const int* in_sizes, int n_in,
                              void* d_out, int out_size, void* d_ws, size_t ws_size,
                              hipStream_t stream)
{
    const float* z      = (const float*)d_in[0];   // [B, D] f32
    const int*   tattr  = (const int*)d_in[1];     // [B, A] i32
    const float* train  = (const float*)d_in[2];   // [N, D] f32
    const int*   trattr = (const int*)d_in[3];     // [N, A] i32
    float* out = (float*)d_out;

    const int B = in_sizes[0] / D;     // 256
    const int N = in_sizes[2] / D;     // 50000

    // ws layout
    char* ws = (char*)d_ws;
    int*      counters = (int*)ws;      ws += (size_t)B * CSTRIDE * sizeof(int);
    unsigned* bucket   = (unsigned*)ws; ws += (size_t)B * SLOTS * sizeof(unsigned);

    const int ctotal = B * CSTRIDE;
    zero_kernel<<<(ctotal + 255) / 256, 256, 0, stream>>>(counters, out, ctotal);
    match_kernel<<<(N + 255) / 256, 256, 0, stream>>>(trattr, tattr, bucket, counters, N);
    dot_topk_kernel<<<B, 1024, 0, stream>>>(train, z, bucket, counters, out, B);
}